// Round 4
// baseline (254.185 us; speedup 1.0000x reference)
//
#include <hip/hip_runtime.h>
#include <stdint.h>

// GAT layer on MI355X: B=8, N=2048, F=128.
// h = x@W^T ; s1=h@a1 ; s2=h@a2 ; e=leaky(s1[i]+s2[j]); masked softmax; out=attn@h
//
// R4: R3 (64-row blocks, halved hT traffic) was latency-bound, not BW-bound:
// 1 block/CU means every __syncthreads' implicit vmcnt(0) drain stalls the
// whole CU (~70us vs 43us BW floor). Fix = T3/T4 counted-vmcnt pipeline:
// raw s_barrier + s_waitcnt vmcnt(12); staging loads stay in flight across
// barriers. LDS ring-4 per j-half (128KB), stage depth-2, adj/s2 reg depth-1.
// Per-wave issue windows (bounded by the asm waits) make vmcnt(12) correct
// independent of compiler reordering inside a window; adj/s2 register deps
// are compiler-tracked. Full unroll -> all ring indices compile-time.
//
// K1 (gat_h): unchanged: W fp32->bf16 swizzled LDS once/block; split-precision
//     x(hi+lo) MFMA; writes hT CHUNKED (16KB chunks of 64 j, HC64 swizzle in
//     the GLOBAL layout -> K2 staging is an identity copy).

#define B_ 8
#define N_ 2048
#define FD 128
#define ALPHA_ 0.2f
#define TJ 64
#define NCHL 16                   // chunks per j-half (1024/64)
#define CHUNK_U4 1024             // 128 o x 8 u4 per 64-j chunk (16 KB)

typedef __attribute__((ext_vector_type(8))) short short8;
typedef __attribute__((ext_vector_type(4))) float f32x4;

// 4-bit XOR swizzle for the 128x128 W tile in gat_h (16B-chunk units)
#define HCHUNK(o, jc) ((((o) * 16) + ((jc) ^ ((o) & 15))) * 8)  // ushort offset
// 3-bit XOR swizzle for 128x64 hT chunks (uint4 units): row o, 16B-chunk jc(0..7)
#define HC64(o, jc) ((o) * 8 + ((jc) ^ ((o) & 7)))              // uint4 index

__device__ __forceinline__ float bf2f(unsigned short u) {
    union { uint32_t i; float f; } v; v.i = ((uint32_t)u) << 16; return v.f;
}
__device__ __forceinline__ unsigned short f2bf(float f) {
    union { float f; uint32_t i; } v; v.f = f;
    uint32_t x = v.i;
    uint32_t r = (x + 0x7fffu + ((x >> 16) & 1u)) >> 16;  // RNE
    return (unsigned short)r;
}

// async global->LDS, 16B per lane. lds dst must be wave-uniform base;
// HW writes base + lane*16 (m104/m108). Our staging is an identity copy.
__device__ __forceinline__ void gl2lds16(const uint4* g, uint4* l) {
    __builtin_amdgcn_global_load_lds(
        (const __attribute__((address_space(1))) uint32_t*)g,
        (__attribute__((address_space(3))) uint32_t*)l, 16, 0, 0);
}

// ---------------------------------------------------------------------------
// Kernel 1: h = x@W^T via split-bf16 MFMA; writes chunked hT + s1/s2.
// 256 blocks x 256 threads; block = 64 rows x 128 outs; wave w: rows w*16..+16.
// C/D: col=lane&15, row=quad*4+reg  (m89/m91-verified layout).
// ---------------------------------------------------------------------------
__global__ __launch_bounds__(256) void gat_h(
    const float* __restrict__ x,
    const float* __restrict__ W,
    const float* __restrict__ a,
    unsigned short* __restrict__ hT,   // chunked: [b][kc][HC64(o,jc)*8 + (j&7)]
    float* __restrict__ s1o, float* __restrict__ s2o)
{
    __shared__ __align__(16) unsigned short Wlds[FD * FD];  // 32KB, swizzled

    const int bid = blockIdx.x;
    const int tid = threadIdx.x;
    const int w = tid >> 6;
    const int lane = tid & 63;
    const int m = lane & 15;
    const int quad = lane >> 4;
    const int arow = bid * 64 + w * 16 + m;   // A-operand row for this lane

    // ---- stage W (fp32 -> bf16) into swizzled LDS, once per block ----
#pragma unroll
    for (int it = 0; it < 8; it++) {
        int cid = it * 256 + tid;          // 2048 16B-chunks
        int o = cid >> 4, kc = cid & 15;
        const float* wp = W + (size_t)o * FD + kc * 8;
        float4 w0 = *(const float4*)wp;
        float4 w1 = *(const float4*)(wp + 4);
        uint4 pk;
        pk.x = (uint32_t)f2bf(w0.x) | ((uint32_t)f2bf(w0.y) << 16);
        pk.y = (uint32_t)f2bf(w0.z) | ((uint32_t)f2bf(w0.w) << 16);
        pk.z = (uint32_t)f2bf(w1.x) | ((uint32_t)f2bf(w1.y) << 16);
        pk.w = (uint32_t)f2bf(w1.z) | ((uint32_t)f2bf(w1.w) << 16);
        *(uint4*)&Wlds[HCHUNK(o, kc)] = pk;
    }
    __syncthreads();

    f32x4 acc[8];
#pragma unroll
    for (int ot = 0; ot < 8; ot++) acc[ot] = (f32x4){0.f, 0.f, 0.f, 0.f};

#pragma unroll
    for (int ks = 0; ks < 4; ks++) {
        const float* xp = x + (size_t)arow * FD + ks * 32 + quad * 8;
        float4 x0 = *(const float4*)xp;
        float4 x1 = *(const float4*)(xp + 4);
        float xv[8] = {x0.x, x0.y, x0.z, x0.w, x1.x, x1.y, x1.z, x1.w};
        union { unsigned short us[8]; short8 v; } ahi, alo;
#pragma unroll
        for (int jj = 0; jj < 8; jj++) {
            unsigned short hi = f2bf(xv[jj]);
            ahi.us[jj] = hi;
            alo.us[jj] = f2bf(xv[jj] - bf2f(hi));
        }
#pragma unroll
        for (int ot = 0; ot < 8; ot++) {
            union { uint4 u; short8 v; } bw;
            bw.u = *(const uint4*)&Wlds[HCHUNK(ot * 16 + m, ks * 4 + quad)];
            acc[ot] = __builtin_amdgcn_mfma_f32_16x16x32_bf16(ahi.v, bw.v, acc[ot], 0, 0, 0);
            acc[ot] = __builtin_amdgcn_mfma_f32_16x16x32_bf16(alo.v, bw.v, acc[ot], 0, 0, 0);
        }
    }

    // Epilogue: store hT (chunked+swizzled, bf16) + s1/s2 partial reduce.
    const int rc0 = bid * 64 + w * 16 + quad * 4;  // C rows rc0..rc0+3 (= j)
    const int bb = rc0 >> 11;                      // batch
    const int jb = rc0 & (N_ - 1);
    const int kc = jb >> 6;                        // chunk
    const int jcl = (jb & 63) >> 3;                // 16B-chunk in chunk
    const int off = jb & 7;                        // 0 or 4
    unsigned short* hTb = hT + (size_t)bb * FD * N_ + (size_t)kc * (CHUNK_U4 * 8);
    float s1p[4] = {0.f, 0.f, 0.f, 0.f};
    float s2p[4] = {0.f, 0.f, 0.f, 0.f};
#pragma unroll
    for (int ot = 0; ot < 8; ot++) {
        const int o = ot * 16 + m;
        uint2 pk;
        pk.x = (uint32_t)f2bf(acc[ot][0]) | ((uint32_t)f2bf(acc[ot][1]) << 16);
        pk.y = (uint32_t)f2bf(acc[ot][2]) | ((uint32_t)f2bf(acc[ot][3]) << 16);
        *(uint2*)(hTb + (size_t)HC64(o, jcl) * 8 + off) = pk;
        float a1v = a[o], a2v = a[FD + o];
#pragma unroll
        for (int r = 0; r < 4; r++) {
            s1p[r] += acc[ot][r] * a1v;
            s2p[r] += acc[ot][r] * a2v;
        }
    }
#pragma unroll
    for (int offx = 8; offx >= 1; offx >>= 1) {
#pragma unroll
        for (int r = 0; r < 4; r++) {
            s1p[r] += __shfl_xor(s1p[r], offx);
            s2p[r] += __shfl_xor(s2p[r], offx);
        }
    }
    if (m == 0) {
#pragma unroll
        for (int r = 0; r < 4; r++) {
            s1o[rc0 + r] = s1p[r];
            s2o[rc0 + r] = s2p[r];
        }
    }
}

// ---------------------------------------------------------------------------
// Kernel 2: fused masked-softmax + PV (MFMA), counted-vmcnt pipeline.
// 256 blocks (b=bid&7 XCD-pin, i0=(bid>>3)*64) x 512 thr. Wave w: rh=w>>1
// rows [i0+rh*16,+16), jh=w&1 j in [jh*1024,+1024). LDS ring-4 per jh,
// stage depth-2 via global_load_lds; adj/s2 reg depth-1; raw s_barrier +
// s_waitcnt vmcnt(12) (never 0 in steady state).
// ---------------------------------------------------------------------------
struct RegSet { int4 a[4]; float4 s[4]; };

__global__ __launch_bounds__(512, 2) void gat_attn(
    const int* __restrict__ adj,
    const unsigned short* __restrict__ hT,
    const float* __restrict__ s1,
    const float* __restrict__ s2,
    float* __restrict__ out)
{
    __shared__ __align__(16) uint4 hbuf[2][4][CHUNK_U4];  // [jh][ring4], 128 KB
    __shared__ float rsx[4][16];                          // per-rh rowsums (jh=1)

    const int bid = blockIdx.x;
    const int b = bid & 7;              // batch -> XCD pin
    const int ib = bid >> 3;            // 0..31
    const int i0 = ib * 64;
    const int tid = threadIdx.x;
    const int lane = tid & 63;
    const int w = tid >> 6;             // 0..7
    const int jh = w & 1;               // j-half
    const int rh = w >> 1;              // row-group 0..3
    const int m = lane & 15;
    const int quad = lane >> 4;

    const int irow = i0 + rh * 16 + m;     // this lane's P row (A-frag m)
    const float s1v = s1[b * N_ + irow];
    const int* adjrow = adj + ((size_t)(b * N_ + irow)) * N_ + jh * 1024;
    const uint4* hTc = (const uint4*)(hT + (size_t)b * FD * N_)
                       + (size_t)jh * NCHL * CHUNK_U4;
    const float* s2b = s2 + b * N_ + jh * 1024;

    f32x4 acc[8];
#pragma unroll
    for (int ot = 0; ot < 8; ot++) acc[ot] = (f32x4){0.f, 0.f, 0.f, 0.f};
    float rs_loc = 0.f;

    RegSet RA, RB;

    // ---- prologue ----
    // S(c0) FIRST, pinned by a compiler memory fence so its issue-order
    // position is guaranteed (vmcnt accounting below needs >=12 ops after it).
#pragma unroll
    for (int q = 0; q < 4; q++)
        gl2lds16(&hTc[(rh * 4 + q) * 64 + lane], &hbuf[jh][0][(rh * 4 + q) * 64]);
    asm volatile("" ::: "memory");
    // R(c0) (compiler-tracked register deps) + S(c1).
#pragma unroll
    for (int ks = 0; ks < 2; ks++) {
        RA.a[2 * ks]     = *(const int4*)(adjrow + ks * 32 + quad * 8);
        RA.a[2 * ks + 1] = *(const int4*)(adjrow + ks * 32 + quad * 8 + 4);
        RA.s[2 * ks]     = *(const float4*)(s2b + ks * 32 + quad * 8);
        RA.s[2 * ks + 1] = *(const float4*)(s2b + ks * 32 + quad * 8 + 4);
    }
#pragma unroll
    for (int q = 0; q < 4; q++)
        gl2lds16(&hTc[(size_t)CHUNK_U4 + (rh * 4 + q) * 64 + lane],
                 &hbuf[jh][1][(rh * 4 + q) * 64]);

    // ---- iteration macro ----
    // Per iter K: [issue R(c_{K+1}) -> RN] [s_waitcnt vmcnt(12|0)] [s_barrier]
    // [issue S(c_{K+2}) -> slot (K+2)&3] [compute cK from slot K&3, RC].
    // vmcnt(12) covers S(cK): worst-case ops issued after it within the asm
    // windows = S(c_{K+1})x4 + R(c_{K+1})x8. R-reg uses are compiler-waited.
#define GAT_ITER(K, RC, RN)                                                    \
    {                                                                          \
        if ((K) + 1 < NCHL) {                                                  \
            const int j1 = ((K) + 1) * TJ;                                     \
            RN.a[0] = *(const int4*)(adjrow + j1 + quad * 8);                  \
            RN.a[1] = *(const int4*)(adjrow + j1 + quad * 8 + 4);              \
            RN.a[2] = *(const int4*)(adjrow + j1 + 32 + quad * 8);             \
            RN.a[3] = *(const int4*)(adjrow + j1 + 32 + quad * 8 + 4);         \
            RN.s[0] = *(const float4*)(s2b + j1 + quad * 8);                   \
            RN.s[1] = *(const float4*)(s2b + j1 + quad * 8 + 4);               \
            RN.s[2] = *(const float4*)(s2b + j1 + 32 + quad * 8);              \
            RN.s[3] = *(const float4*)(s2b + j1 + 32 + quad * 8 + 4);          \
        }                                                                      \
        if ((K) < NCHL - 1) asm volatile("s_waitcnt vmcnt(12)" ::: "memory");  \
        else                asm volatile("s_waitcnt vmcnt(0)" ::: "memory");   \
        __builtin_amdgcn_s_barrier();                                          \
        asm volatile("" ::: "memory");                                         \
        if ((K) + 2 < NCHL) {                                                  \
            _Pragma("unroll")                                                  \
            for (int q = 0; q < 4; q++)                                        \
                gl2lds16(&hTc[(size_t)((K) + 2) * CHUNK_U4 + (rh * 4 + q) * 64 \
                              + lane],                                         \
                         &hbuf[jh][((K) + 2) & 3][(rh * 4 + q) * 64]);         \
        }                                                                      \
        _Pragma("unroll")                                                      \
        for (int ks = 0; ks < 2; ks++) {                                       \
            float4 sa = RC.s[2 * ks], sb = RC.s[2 * ks + 1];                   \
            float sarr[8] = {sa.x, sa.y, sa.z, sa.w, sb.x, sb.y, sb.z, sb.w};  \
            int4 A0 = RC.a[2 * ks], A1 = RC.a[2 * ks + 1];                     \
            int aarr[8] = {A0.x, A0.y, A0.z, A0.w, A1.x, A1.y, A1.z, A1.w};    \
            union { unsigned short us[8]; short8 v; } af;                      \
            _Pragma("unroll")                                                  \
            for (int jj = 0; jj < 8; jj++) {                                   \
                float e = s1v + sarr[jj];                                      \
                e = (e > 0.f) ? e : (ALPHA_ * e);                              \
                float p = (aarr[jj] > 0) ? __expf(e) : 0.f;                    \
                rs_loc += p;                                                   \
                af.us[jj] = f2bf(p);                                           \
            }                                                                  \
            const int jc = ks * 4 + quad;                                      \
            _Pragma("unroll")                                                  \
            for (int ot = 0; ot < 8; ot++) {                                   \
                const int o = ot * 16 + m;                                     \
                union { uint4 u; short8 v; } bf;                               \
                bf.u = *(const uint4*)&hbuf[jh][(K) & 3][HC64(o, jc)];         \
                acc[ot] = __builtin_amdgcn_mfma_f32_16x16x32_bf16(             \
                    af.v, bf.v, acc[ot], 0, 0, 0);                             \
            }                                                                  \
        }                                                                      \
    }

    GAT_ITER(0,  RA, RB)
    GAT_ITER(1,  RB, RA)
    GAT_ITER(2,  RA, RB)
    GAT_ITER(3,  RB, RA)
    GAT_ITER(4,  RA, RB)
    GAT_ITER(5,  RB, RA)
    GAT_ITER(6,  RA, RB)
    GAT_ITER(7,  RB, RA)
    GAT_ITER(8,  RA, RB)
    GAT_ITER(9,  RB, RA)
    GAT_ITER(10, RA, RB)
    GAT_ITER(11, RB, RA)
    GAT_ITER(12, RA, RB)
    GAT_ITER(13, RB, RA)
    GAT_ITER(14, RA, RB)
    GAT_ITER(15, RB, RA)
#undef GAT_ITER

    // ---- rowsum: lanes m, m+16, m+32, m+48 hold partials of row m ----
    rs_loc += __shfl_xor(rs_loc, 16);
    rs_loc += __shfl_xor(rs_loc, 32);

    // ---- cross-j-half combine via LDS ----
    // xch overlays hbuf[0][0..2] (33.3KB); jh0's last compute reads slot 3
    // (48-64KB) and jh1's reads are in the upper half -> disjoint. The
    // __syncthreads below orders writer(jh1) vs reader(jh0).
    float* xch = (float*)&hbuf[0][0][0];   // [64 rows][130] floats
    if (jh == 1) {
#pragma unroll
        for (int ot = 0; ot < 8; ot++)
#pragma unroll
            for (int r = 0; r < 4; r++)
                xch[(rh * 16 + quad * 4 + r) * 130 + ot * 16 + m] = acc[ot][r];
        if (quad == 0) rsx[rh][m] = rs_loc;
    }
    __syncthreads();
    if (jh == 0) {
        float rinv[4];
#pragma unroll
        for (int r = 0; r < 4; r++) {
            const int p = quad * 4 + r;
            rinv[r] = 1.0f / (__shfl(rs_loc, p) + rsx[rh][p]);
        }
        float* outp = out + (size_t)(b * N_ + i0 + rh * 16) * FD;
#pragma unroll
        for (int ot = 0; ot < 8; ot++) {
            const int col = ot * 16 + m;
#pragma unroll
            for (int r = 0; r < 4; r++) {
                float v = acc[ot][r] + xch[(rh * 16 + quad * 4 + r) * 130 + col];
                outp[(size_t)(quad * 4 + r) * FD + col] = v * rinv[r];
            }
        }
    }
}

// ---------------------------------------------------------------------------
extern "C" void kernel_launch(void* const* d_in, const int* in_sizes, int n_in,
                              void* d_out, int out_size, void* d_ws, size_t ws_size,
                              hipStream_t stream) {
    const void* xv = d_in[0];
    const void* adjv = d_in[1];
    const void* Wv = d_in[2];
    const void* av = d_in[3];
    for (int i = 0; i < n_in; i++) {
        switch (in_sizes[i]) {
            case 2097152:  xv = d_in[i]; break;
            case 33554432: adjv = d_in[i]; break;
            case 16384:    Wv = d_in[i]; break;
            case 256:      av = d_in[i]; break;
            default: break;
        }
    }
    const float* x = (const float*)xv;
    const int* adj = (const int*)adjv;
    const float* W = (const float*)Wv;
    const float* a = (const float*)av;
    float* out = (float*)d_out;

    // ws: hT 4MB | s1 64KB | s2 64KB
    char* p = (char*)d_ws;
    unsigned short* hT = (unsigned short*)p;  p += (size_t)B_ * FD * N_ * 2;
    float* s1 = (float*)p;                    p += (size_t)B_ * N_ * 4;
    float* s2 = (float*)p;

    gat_h<<<256, 256, 0, stream>>>(x, W, a, hT, s1, s2);
    gat_attn<<<256, 512, 0, stream>>>(adj, hT, s1, s2, out);
}

// Round 5
// 246.715 us; speedup vs baseline: 1.0303x; 1.0303x over previous
//
#include <hip/hip_runtime.h>
#include <stdint.h>

// GAT layer on MI355X: B=8, N=2048, F=128.
// h = x@W^T ; s1=h@a1 ; s2=h@a2 ; e=leaky(s1[i]+s2[j]); masked softmax; out=attn@h
//
// R5: R4's counted-vmcnt pipeline was wrecked by register spills (WRITE_SIZE
// 53MB vs 11.5MB expected = scratch traffic; 64 VGPRs of RegSets + acc 32
// overflowed the 128 budget). Fix: s2 lives in LDS (8KB, staged once,
// quad-broadcast reads), adj keeps the 2-deep register pipeline (32 VGPR).
// Loop VMEM per iter = 4 adj loads + 4 global_load_lds -> at the pre-barrier
// wait, ops newer than S(c_K) = R(cK)4 + S(cK+1)4 + R(cK+1)4 = 12 exactly
// -> s_waitcnt vmcnt(12) (tail vmcnt(4)); staging stays in flight across
// barriers (T3/T4). Fences after each S-group pin the issue order the
// count relies on. One-time lgkmcnt(0) before first barrier (raw s_barrier
// doesn't drain; s2 ds_writes must be visible).
//
// K1 (gat_h): unchanged: W fp32->bf16 swizzled LDS once/block; split-precision
//     x(hi+lo) MFMA; writes hT CHUNKED (16KB chunks of 64 j, HC64 swizzle in
//     the GLOBAL layout -> K2 staging is an identity copy).

#define B_ 8
#define N_ 2048
#define FD 128
#define ALPHA_ 0.2f
#define TJ 64
#define NCHL 16                   // chunks per j-half (1024/64)
#define CHUNK_U4 1024             // 128 o x 8 u4 per 64-j chunk (16 KB)

typedef __attribute__((ext_vector_type(8))) short short8;
typedef __attribute__((ext_vector_type(4))) float f32x4;

// 4-bit XOR swizzle for the 128x128 W tile in gat_h (16B-chunk units)
#define HCHUNK(o, jc) ((((o) * 16) + ((jc) ^ ((o) & 15))) * 8)  // ushort offset
// 3-bit XOR swizzle for 128x64 hT chunks (uint4 units): row o, 16B-chunk jc(0..7)
#define HC64(o, jc) ((o) * 8 + ((jc) ^ ((o) & 7)))              // uint4 index

__device__ __forceinline__ float bf2f(unsigned short u) {
    union { uint32_t i; float f; } v; v.i = ((uint32_t)u) << 16; return v.f;
}
__device__ __forceinline__ unsigned short f2bf(float f) {
    union { float f; uint32_t i; } v; v.f = f;
    uint32_t x = v.i;
    uint32_t r = (x + 0x7fffu + ((x >> 16) & 1u)) >> 16;  // RNE
    return (unsigned short)r;
}

// async global->LDS, 16B per lane. lds dst must be wave-uniform base;
// HW writes base + lane*16 (m104/m108). Our staging is an identity copy.
__device__ __forceinline__ void gl2lds16(const uint4* g, uint4* l) {
    __builtin_amdgcn_global_load_lds(
        (const __attribute__((address_space(1))) uint32_t*)g,
        (__attribute__((address_space(3))) uint32_t*)l, 16, 0, 0);
}

// ---------------------------------------------------------------------------
// Kernel 1: h = x@W^T via split-bf16 MFMA; writes chunked hT + s1/s2.
// 256 blocks x 256 threads; block = 64 rows x 128 outs; wave w: rows w*16..+16.
// C/D: col=lane&15, row=quad*4+reg  (m89/m91-verified layout).
// ---------------------------------------------------------------------------
__global__ __launch_bounds__(256) void gat_h(
    const float* __restrict__ x,
    const float* __restrict__ W,
    const float* __restrict__ a,
    unsigned short* __restrict__ hT,   // chunked: [b][kc][HC64(o,jc)*8 + (j&7)]
    float* __restrict__ s1o, float* __restrict__ s2o)
{
    __shared__ __align__(16) unsigned short Wlds[FD * FD];  // 32KB, swizzled

    const int bid = blockIdx.x;
    const int tid = threadIdx.x;
    const int w = tid >> 6;
    const int lane = tid & 63;
    const int m = lane & 15;
    const int quad = lane >> 4;
    const int arow = bid * 64 + w * 16 + m;   // A-operand row for this lane

    // ---- stage W (fp32 -> bf16) into swizzled LDS, once per block ----
#pragma unroll
    for (int it = 0; it < 8; it++) {
        int cid = it * 256 + tid;          // 2048 16B-chunks
        int o = cid >> 4, kc = cid & 15;
        const float* wp = W + (size_t)o * FD + kc * 8;
        float4 w0 = *(const float4*)wp;
        float4 w1 = *(const float4*)(wp + 4);
        uint4 pk;
        pk.x = (uint32_t)f2bf(w0.x) | ((uint32_t)f2bf(w0.y) << 16);
        pk.y = (uint32_t)f2bf(w0.z) | ((uint32_t)f2bf(w0.w) << 16);
        pk.z = (uint32_t)f2bf(w1.x) | ((uint32_t)f2bf(w1.y) << 16);
        pk.w = (uint32_t)f2bf(w1.z) | ((uint32_t)f2bf(w1.w) << 16);
        *(uint4*)&Wlds[HCHUNK(o, kc)] = pk;
    }
    __syncthreads();

    f32x4 acc[8];
#pragma unroll
    for (int ot = 0; ot < 8; ot++) acc[ot] = (f32x4){0.f, 0.f, 0.f, 0.f};

#pragma unroll
    for (int ks = 0; ks < 4; ks++) {
        const float* xp = x + (size_t)arow * FD + ks * 32 + quad * 8;
        float4 x0 = *(const float4*)xp;
        float4 x1 = *(const float4*)(xp + 4);
        float xv[8] = {x0.x, x0.y, x0.z, x0.w, x1.x, x1.y, x1.z, x1.w};
        union { unsigned short us[8]; short8 v; } ahi, alo;
#pragma unroll
        for (int jj = 0; jj < 8; jj++) {
            unsigned short hi = f2bf(xv[jj]);
            ahi.us[jj] = hi;
            alo.us[jj] = f2bf(xv[jj] - bf2f(hi));
        }
#pragma unroll
        for (int ot = 0; ot < 8; ot++) {
            union { uint4 u; short8 v; } bw;
            bw.u = *(const uint4*)&Wlds[HCHUNK(ot * 16 + m, ks * 4 + quad)];
            acc[ot] = __builtin_amdgcn_mfma_f32_16x16x32_bf16(ahi.v, bw.v, acc[ot], 0, 0, 0);
            acc[ot] = __builtin_amdgcn_mfma_f32_16x16x32_bf16(alo.v, bw.v, acc[ot], 0, 0, 0);
        }
    }

    // Epilogue: store hT (chunked+swizzled, bf16) + s1/s2 partial reduce.
    const int rc0 = bid * 64 + w * 16 + quad * 4;  // C rows rc0..rc0+3 (= j)
    const int bb = rc0 >> 11;                      // batch
    const int jb = rc0 & (N_ - 1);
    const int kc = jb >> 6;                        // chunk
    const int jcl = (jb & 63) >> 3;                // 16B-chunk in chunk
    const int off = jb & 7;                        // 0 or 4
    unsigned short* hTb = hT + (size_t)bb * FD * N_ + (size_t)kc * (CHUNK_U4 * 8);
    float s1p[4] = {0.f, 0.f, 0.f, 0.f};
    float s2p[4] = {0.f, 0.f, 0.f, 0.f};
#pragma unroll
    for (int ot = 0; ot < 8; ot++) {
        const int o = ot * 16 + m;
        uint2 pk;
        pk.x = (uint32_t)f2bf(acc[ot][0]) | ((uint32_t)f2bf(acc[ot][1]) << 16);
        pk.y = (uint32_t)f2bf(acc[ot][2]) | ((uint32_t)f2bf(acc[ot][3]) << 16);
        *(uint2*)(hTb + (size_t)HC64(o, jcl) * 8 + off) = pk;
        float a1v = a[o], a2v = a[FD + o];
#pragma unroll
        for (int r = 0; r < 4; r++) {
            s1p[r] += acc[ot][r] * a1v;
            s2p[r] += acc[ot][r] * a2v;
        }
    }
#pragma unroll
    for (int offx = 8; offx >= 1; offx >>= 1) {
#pragma unroll
        for (int r = 0; r < 4; r++) {
            s1p[r] += __shfl_xor(s1p[r], offx);
            s2p[r] += __shfl_xor(s2p[r], offx);
        }
    }
    if (m == 0) {
#pragma unroll
        for (int r = 0; r < 4; r++) {
            s1o[rc0 + r] = s1p[r];
            s2o[rc0 + r] = s2p[r];
        }
    }
}

// ---------------------------------------------------------------------------
// Kernel 2: fused masked-softmax + PV (MFMA), counted-vmcnt pipeline, low-VGPR.
// 256 blocks (b=bid&7 XCD-pin, i0=(bid>>3)*64) x 512 thr. Wave w: rh=w>>1
// rows [i0+rh*16,+16), jh=w&1 j in [jh*1024,+1024). LDS ring-4 per jh
// (128KB) + s2 resident in LDS (8KB). adj reg pipeline depth-2 (32 VGPR).
// Raw s_barrier + s_waitcnt vmcnt(12) (tail 4) -- never 0 in steady state.
// ---------------------------------------------------------------------------
struct AdjSet { int4 a[4]; };

__global__ __launch_bounds__(512, 2) void gat_attn(
    const int* __restrict__ adj,
    const unsigned short* __restrict__ hT,
    const float* __restrict__ s1,
    const float* __restrict__ s2,
    float* __restrict__ out)
{
    __shared__ __align__(16) uint4 hbuf[2][4][CHUNK_U4];  // [jh][ring4], 128 KB
    __shared__ float s2lds[2 * 1024];                     // 8 KB, whole row
    __shared__ float rsx[4][16];                          // per-rh rowsums (jh=1)

    const int bid = blockIdx.x;
    const int b = bid & 7;              // batch -> XCD pin
    const int ib = bid >> 3;            // 0..31
    const int i0 = ib * 64;
    const int tid = threadIdx.x;
    const int lane = tid & 63;
    const int w = tid >> 6;             // 0..7
    const int jh = w & 1;               // j-half
    const int rh = w >> 1;              // row-group 0..3
    const int m = lane & 15;
    const int quad = lane >> 4;

    const int irow = i0 + rh * 16 + m;     // this lane's P row (A-frag m)
    const float s1v = s1[b * N_ + irow];
    const int* adjrow = adj + ((size_t)(b * N_ + irow)) * N_ + jh * 1024;
    const uint4* hTc = (const uint4*)(hT + (size_t)b * FD * N_)
                       + (size_t)jh * NCHL * CHUNK_U4;

    f32x4 acc[8];
#pragma unroll
    for (int ot = 0; ot < 8; ot++) acc[ot] = (f32x4){0.f, 0.f, 0.f, 0.f};
    float rs_loc = 0.f;

    AdjSet RA, RB;

    // ---- prologue ----
    // s2 -> LDS (512 thr x float4 = 2048 floats). The ds_write forces the
    // compiler to drain its own load, so it doesn't perturb vmcnt counting.
    {
        float4 v = *(const float4*)(s2 + b * N_ + tid * 4);
        *(float4*)&s2lds[tid * 4] = v;
    }
    asm volatile("" ::: "memory");
    // S(c0) FIRST (oldest in the vmcnt queue), pinned by fences.
#pragma unroll
    for (int q = 0; q < 4; q++)
        gl2lds16(&hTc[(rh * 4 + q) * 64 + lane], &hbuf[jh][0][(rh * 4 + q) * 64]);
    asm volatile("" ::: "memory");
    // R_adj(c0) + S(c1).
#pragma unroll
    for (int ks = 0; ks < 2; ks++) {
        RA.a[2 * ks]     = *(const int4*)(adjrow + ks * 32 + quad * 8);
        RA.a[2 * ks + 1] = *(const int4*)(adjrow + ks * 32 + quad * 8 + 4);
    }
#pragma unroll
    for (int q = 0; q < 4; q++)
        gl2lds16(&hTc[(size_t)CHUNK_U4 + (rh * 4 + q) * 64 + lane],
                 &hbuf[jh][1][(rh * 4 + q) * 64]);
    asm volatile("s_waitcnt lgkmcnt(0)" ::: "memory");  // s2 ds_writes visible

    // ---- iteration macro ----
    // Iter K: [issue R_adj(c_{K+1}) -> RN] [s_waitcnt vmcnt(12|4)] [s_barrier]
    // [issue S(c_{K+2}) -> slot (K+2)&3, fence] [compute cK: slot K&3, RC,
    // s2 from LDS]. At the wait, ops newer than S(cK) = R(cK)4 + S(cK+1)4 +
    // R(cK+1)4 = 12 exactly; adj register uses are compiler-waited.
#define GAT_ITER(K, RC, RN)                                                    \
    {                                                                          \
        if ((K) + 1 < NCHL) {                                                  \
            const int j1 = ((K) + 1) * TJ;                                     \
            RN.a[0] = *(const int4*)(adjrow + j1 + quad * 8);                  \
            RN.a[1] = *(const int4*)(adjrow + j1 + quad * 8 + 4);              \
            RN.a[2] = *(const int4*)(adjrow + j1 + 32 + quad * 8);             \
            RN.a[3] = *(const int4*)(adjrow + j1 + 32 + quad * 8 + 4);         \
        }                                                                      \
        if ((K) < NCHL - 1) asm volatile("s_waitcnt vmcnt(12)" ::: "memory");  \
        else                asm volatile("s_waitcnt vmcnt(4)" ::: "memory");   \
        __builtin_amdgcn_s_barrier();                                          \
        asm volatile("" ::: "memory");                                         \
        if ((K) + 2 < NCHL) {                                                  \
            _Pragma("unroll")                                                  \
            for (int q = 0; q < 4; q++)                                        \
                gl2lds16(&hTc[(size_t)((K) + 2) * CHUNK_U4 + (rh * 4 + q) * 64 \
                              + lane],                                         \
                         &hbuf[jh][((K) + 2) & 3][(rh * 4 + q) * 64]);         \
        }                                                                      \
        asm volatile("" ::: "memory");                                         \
        _Pragma("unroll")                                                      \
        for (int ks = 0; ks < 2; ks++) {                                       \
            const float* sp = &s2lds[jh * 1024 + (K) * TJ + ks * 32 + quad * 8]; \
            float4 sa = *(const float4*)sp;                                    \
            float4 sb = *(const float4*)(sp + 4);                              \
            float sarr[8] = {sa.x, sa.y, sa.z, sa.w, sb.x, sb.y, sb.z, sb.w};  \
            int4 A0 = RC.a[2 * ks], A1 = RC.a[2 * ks + 1];                     \
            int aarr[8] = {A0.x, A0.y, A0.z, A0.w, A1.x, A1.y, A1.z, A1.w};    \
            union { unsigned short us[8]; short8 v; } af;                      \
            _Pragma("unroll")                                                  \
            for (int jj = 0; jj < 8; jj++) {                                   \
                float e = s1v + sarr[jj];                                      \
                e = (e > 0.f) ? e : (ALPHA_ * e);                              \
                float p = (aarr[jj] > 0) ? __expf(e) : 0.f;                    \
                rs_loc += p;                                                   \
                af.us[jj] = f2bf(p);                                           \
            }                                                                  \
            const int jc = ks * 4 + quad;                                      \
            _Pragma("unroll")                                                  \
            for (int ot = 0; ot < 8; ot++) {                                   \
                const int o = ot * 16 + m;                                     \
                union { uint4 u; short8 v; } bf;                               \
                bf.u = *(const uint4*)&hbuf[jh][(K) & 3][HC64(o, jc)];         \
                acc[ot] = __builtin_amdgcn_mfma_f32_16x16x32_bf16(             \
                    af.v, bf.v, acc[ot], 0, 0, 0);                             \
            }                                                                  \
        }                                                                      \
    }

    GAT_ITER(0,  RA, RB)
    GAT_ITER(1,  RB, RA)
    GAT_ITER(2,  RA, RB)
    GAT_ITER(3,  RB, RA)
    GAT_ITER(4,  RA, RB)
    GAT_ITER(5,  RB, RA)
    GAT_ITER(6,  RA, RB)
    GAT_ITER(7,  RB, RA)
    GAT_ITER(8,  RA, RB)
    GAT_ITER(9,  RB, RA)
    GAT_ITER(10, RA, RB)
    GAT_ITER(11, RB, RA)
    GAT_ITER(12, RA, RB)
    GAT_ITER(13, RB, RA)
    GAT_ITER(14, RA, RB)
    GAT_ITER(15, RB, RA)
#undef GAT_ITER

    // ---- rowsum: lanes m, m+16, m+32, m+48 hold partials of row m ----
    rs_loc += __shfl_xor(rs_loc, 16);
    rs_loc += __shfl_xor(rs_loc, 32);

    // ---- cross-j-half combine via LDS ----
    // xch overlays hbuf[0][0..2] (33.3KB); compute c15 reads slots 3 only
    // (jh0: 48-64KB, jh1: 112-128KB) -> disjoint. __syncthreads orders
    // writer(jh1) vs reader(jh0).
    float* xch = (float*)&hbuf[0][0][0];   // [64 rows][130] floats
    if (jh == 1) {
#pragma unroll
        for (int ot = 0; ot < 8; ot++)
#pragma unroll
            for (int r = 0; r < 4; r++)
                xch[(rh * 16 + quad * 4 + r) * 130 + ot * 16 + m] = acc[ot][r];
        if (quad == 0) rsx[rh][m] = rs_loc;
    }
    __syncthreads();
    if (jh == 0) {
        float rinv[4];
#pragma unroll
        for (int r = 0; r < 4; r++) {
            const int p = quad * 4 + r;
            rinv[r] = 1.0f / (__shfl(rs_loc, p) + rsx[rh][p]);
        }
        float* outp = out + (size_t)(b * N_ + i0 + rh * 16) * FD;
#pragma unroll
        for (int ot = 0; ot < 8; ot++) {
            const int col = ot * 16 + m;
#pragma unroll
            for (int r = 0; r < 4; r++) {
                float v = acc[ot][r] + xch[(rh * 16 + quad * 4 + r) * 130 + col];
                outp[(size_t)(quad * 4 + r) * FD + col] = v * rinv[r];
            }
        }
    }
}

// ---------------------------------------------------------------------------
extern "C" void kernel_launch(void* const* d_in, const int* in_sizes, int n_in,
                              void* d_out, int out_size, void* d_ws, size_t ws_size,
                              hipStream_t stream) {
    const void* xv = d_in[0];
    const void* adjv = d_in[1];
    const void* Wv = d_in[2];
    const void* av = d_in[3];
    for (int i = 0; i < n_in; i++) {
        switch (in_sizes[i]) {
            case 2097152:  xv = d_in[i]; break;
            case 33554432: adjv = d_in[i]; break;
            case 16384:    Wv = d_in[i]; break;
            case 256:      av = d_in[i]; break;
            default: break;
        }
    }
    const float* x = (const float*)xv;
    const int* adj = (const int*)adjv;
    const float* W = (const float*)Wv;
    const float* a = (const float*)av;
    float* out = (float*)d_out;

    // ws: hT 4MB | s1 64KB | s2 64KB
    char* p = (char*)d_ws;
    unsigned short* hT = (unsigned short*)p;  p += (size_t)B_ * FD * N_ * 2;
    float* s1 = (float*)p;                    p += (size_t)B_ * N_ * 4;
    float* s2 = (float*)p;

    gat_h<<<256, 256, 0, stream>>>(x, W, a, hT, s1, s2);
    gat_attn<<<256, 512, 0, stream>>>(adj, hT, s1, s2, out);
}

// Round 6
// 225.424 us; speedup vs baseline: 1.1276x; 1.0945x over previous
//
#include <hip/hip_runtime.h>
#include <stdint.h>

// GAT layer on MI355X: B=8, N=2048, F=128.
// h = x@W^T ; s1=h@a1 ; s2=h@a2 ; e=leaky(s1[i]+s2[j]); masked softmax; out=attn@h
//
// R6: counted-vmcnt on R3's ROLLED loop (R3 compiled to VGPR=64, no spill;
// R4/R5's full-unroll macro + fences blew registers to 128 + ~37MB scratch
// traffic -- that, not the schedule, was the regression). Surgical change
// vs R3: (a) fence between the gl2lds group and the adj/s2 register loads
// so staging ops are the OLDEST in the vmcnt queue; (b) replace each
// __syncthreads with s_waitcnt vmcnt(8) + raw s_barrier. vmcnt(8) completes
// S(c_{k+1}) (8 oldest) while the 8 adj/s2 prefetches stay in flight across
// the barrier (T4; m135 oldest-first semantics). adj/s2 register uses are
// compiler-waited. Steady state never drains to 0.
//
// K1 (gat_h): unchanged: W fp32->bf16 swizzled LDS once/block; split-precision
//     x(hi+lo) MFMA; writes hT CHUNKED (16KB chunks of 64 j, HC64 swizzle in
//     the GLOBAL layout -> K2 staging is an identity copy).

#define B_ 8
#define N_ 2048
#define FD 128
#define ALPHA_ 0.2f
#define TJ 64
#define NCHL 16                   // chunks per j-half (1024/64)
#define CHUNK_U4 1024             // 128 o x 8 u4 per 64-j chunk (16 KB)

typedef __attribute__((ext_vector_type(8))) short short8;
typedef __attribute__((ext_vector_type(4))) float f32x4;

// 4-bit XOR swizzle for the 128x128 W tile in gat_h (16B-chunk units)
#define HCHUNK(o, jc) ((((o) * 16) + ((jc) ^ ((o) & 15))) * 8)  // ushort offset
// 3-bit XOR swizzle for 128x64 hT chunks (uint4 units): row o, 16B-chunk jc(0..7)
#define HC64(o, jc) ((o) * 8 + ((jc) ^ ((o) & 7)))              // uint4 index

__device__ __forceinline__ float bf2f(unsigned short u) {
    union { uint32_t i; float f; } v; v.i = ((uint32_t)u) << 16; return v.f;
}
__device__ __forceinline__ unsigned short f2bf(float f) {
    union { float f; uint32_t i; } v; v.f = f;
    uint32_t x = v.i;
    uint32_t r = (x + 0x7fffu + ((x >> 16) & 1u)) >> 16;  // RNE
    return (unsigned short)r;
}

// async global->LDS, 16B per lane. lds dst must be wave-uniform base;
// HW writes base + lane*16 (m104/m108). Our staging is an identity copy.
__device__ __forceinline__ void gl2lds16(const uint4* g, uint4* l) {
    __builtin_amdgcn_global_load_lds(
        (const __attribute__((address_space(1))) uint32_t*)g,
        (__attribute__((address_space(3))) uint32_t*)l, 16, 0, 0);
}

// ---------------------------------------------------------------------------
// Kernel 1: h = x@W^T via split-bf16 MFMA; writes chunked hT + s1/s2.
// 256 blocks x 256 threads; block = 64 rows x 128 outs; wave w: rows w*16..+16.
// C/D: col=lane&15, row=quad*4+reg  (m89/m91-verified layout).
// ---------------------------------------------------------------------------
__global__ __launch_bounds__(256) void gat_h(
    const float* __restrict__ x,
    const float* __restrict__ W,
    const float* __restrict__ a,
    unsigned short* __restrict__ hT,   // chunked: [b][kc][HC64(o,jc)*8 + (j&7)]
    float* __restrict__ s1o, float* __restrict__ s2o)
{
    __shared__ __align__(16) unsigned short Wlds[FD * FD];  // 32KB, swizzled

    const int bid = blockIdx.x;
    const int tid = threadIdx.x;
    const int w = tid >> 6;
    const int lane = tid & 63;
    const int m = lane & 15;
    const int quad = lane >> 4;
    const int arow = bid * 64 + w * 16 + m;   // A-operand row for this lane

    // ---- stage W (fp32 -> bf16) into swizzled LDS, once per block ----
#pragma unroll
    for (int it = 0; it < 8; it++) {
        int cid = it * 256 + tid;          // 2048 16B-chunks
        int o = cid >> 4, kc = cid & 15;
        const float* wp = W + (size_t)o * FD + kc * 8;
        float4 w0 = *(const float4*)wp;
        float4 w1 = *(const float4*)(wp + 4);
        uint4 pk;
        pk.x = (uint32_t)f2bf(w0.x) | ((uint32_t)f2bf(w0.y) << 16);
        pk.y = (uint32_t)f2bf(w0.z) | ((uint32_t)f2bf(w0.w) << 16);
        pk.z = (uint32_t)f2bf(w1.x) | ((uint32_t)f2bf(w1.y) << 16);
        pk.w = (uint32_t)f2bf(w1.z) | ((uint32_t)f2bf(w1.w) << 16);
        *(uint4*)&Wlds[HCHUNK(o, kc)] = pk;
    }
    __syncthreads();

    f32x4 acc[8];
#pragma unroll
    for (int ot = 0; ot < 8; ot++) acc[ot] = (f32x4){0.f, 0.f, 0.f, 0.f};

#pragma unroll
    for (int ks = 0; ks < 4; ks++) {
        const float* xp = x + (size_t)arow * FD + ks * 32 + quad * 8;
        float4 x0 = *(const float4*)xp;
        float4 x1 = *(const float4*)(xp + 4);
        float xv[8] = {x0.x, x0.y, x0.z, x0.w, x1.x, x1.y, x1.z, x1.w};
        union { unsigned short us[8]; short8 v; } ahi, alo;
#pragma unroll
        for (int jj = 0; jj < 8; jj++) {
            unsigned short hi = f2bf(xv[jj]);
            ahi.us[jj] = hi;
            alo.us[jj] = f2bf(xv[jj] - bf2f(hi));
        }
#pragma unroll
        for (int ot = 0; ot < 8; ot++) {
            union { uint4 u; short8 v; } bw;
            bw.u = *(const uint4*)&Wlds[HCHUNK(ot * 16 + m, ks * 4 + quad)];
            acc[ot] = __builtin_amdgcn_mfma_f32_16x16x32_bf16(ahi.v, bw.v, acc[ot], 0, 0, 0);
            acc[ot] = __builtin_amdgcn_mfma_f32_16x16x32_bf16(alo.v, bw.v, acc[ot], 0, 0, 0);
        }
    }

    // Epilogue: store hT (chunked+swizzled, bf16) + s1/s2 partial reduce.
    const int rc0 = bid * 64 + w * 16 + quad * 4;  // C rows rc0..rc0+3 (= j)
    const int bb = rc0 >> 11;                      // batch
    const int jb = rc0 & (N_ - 1);
    const int kc = jb >> 6;                        // chunk
    const int jcl = (jb & 63) >> 3;                // 16B-chunk in chunk
    const int off = jb & 7;                        // 0 or 4
    unsigned short* hTb = hT + (size_t)bb * FD * N_ + (size_t)kc * (CHUNK_U4 * 8);
    float s1p[4] = {0.f, 0.f, 0.f, 0.f};
    float s2p[4] = {0.f, 0.f, 0.f, 0.f};
#pragma unroll
    for (int ot = 0; ot < 8; ot++) {
        const int o = ot * 16 + m;
        uint2 pk;
        pk.x = (uint32_t)f2bf(acc[ot][0]) | ((uint32_t)f2bf(acc[ot][1]) << 16);
        pk.y = (uint32_t)f2bf(acc[ot][2]) | ((uint32_t)f2bf(acc[ot][3]) << 16);
        *(uint2*)(hTb + (size_t)HC64(o, jcl) * 8 + off) = pk;
        float a1v = a[o], a2v = a[FD + o];
#pragma unroll
        for (int r = 0; r < 4; r++) {
            s1p[r] += acc[ot][r] * a1v;
            s2p[r] += acc[ot][r] * a2v;
        }
    }
#pragma unroll
    for (int offx = 8; offx >= 1; offx >>= 1) {
#pragma unroll
        for (int r = 0; r < 4; r++) {
            s1p[r] += __shfl_xor(s1p[r], offx);
            s2p[r] += __shfl_xor(s2p[r], offx);
        }
    }
    if (m == 0) {
#pragma unroll
        for (int r = 0; r < 4; r++) {
            s1o[rc0 + r] = s1p[r];
            s2o[rc0 + r] = s2p[r];
        }
    }
}

// ---------------------------------------------------------------------------
// Kernel 2: fused masked-softmax + PV (MFMA), 64-row blocks, counted vmcnt.
// 256 blocks (b=bid&7 -> XCD-pinned, ib=bid>>3, rows i0=ib*64) x 512 thr.
// Wave w: rh = w>>1 (rows [i0+rh*16,+16)), jh = w&1 (j in [jh*1024,+1024)).
// hT chunk staged once/block/j-half via global_load_lds, double-buffered;
// all 4 rh-waves of a j-half consume the same LDS chunk.
// Per iter: [S(c_{k+1}) 8x gl2lds][fence][R(c_{k+1}) 8x adj/s2 reg loads]
// [compute c_k][vmcnt(8): S done, R stays in flight][s_barrier].
// Epilogue: jh=1 waves push acc/rowsum via LDS; jh=0 combine, divide, write.
// ---------------------------------------------------------------------------
__global__ __launch_bounds__(512, 2) void gat_attn(
    const int* __restrict__ adj,
    const unsigned short* __restrict__ hT,
    const float* __restrict__ s1,
    const float* __restrict__ s2,
    float* __restrict__ out)
{
    __shared__ __align__(16) uint4 hbuf[2][2][CHUNK_U4];  // [jh][buf], 64 KB
    __shared__ float rsx[4][16];                          // per-rh rowsums (jh=1)

    const int bid = blockIdx.x;
    const int b = bid & 7;              // batch -> XCD pin
    const int ib = bid >> 3;            // 0..31
    const int i0 = ib * 64;
    const int tid = threadIdx.x;
    const int lane = tid & 63;
    const int w = tid >> 6;             // 0..7
    const int jh = w & 1;               // j-half
    const int rh = w >> 1;              // row-group 0..3
    const int m = lane & 15;
    const int quad = lane >> 4;

    const int irow = i0 + rh * 16 + m;     // this lane's P row (A-frag m)
    const float s1v = s1[b * N_ + irow];
    const int* adjrow = adj + ((size_t)(b * N_ + irow)) * N_ + jh * 1024;
    const uint4* hTc = (const uint4*)(hT + (size_t)b * FD * N_)
                       + (size_t)jh * NCHL * CHUNK_U4;
    const float* s2b = s2 + b * N_ + jh * 1024;

    // ---- prologue: stage chunk 0 (oldest in vmcnt queue); prefetch k=0 ----
    // 4 rh-waves x 4 instr x 64 lanes = 1024 uint4 = one 16KB chunk.
#pragma unroll
    for (int q = 0; q < 4; q++)
        gl2lds16(&hTc[(rh * 4 + q) * 64 + lane], &hbuf[jh][0][(rh * 4 + q) * 64]);
    asm volatile("" ::: "memory");   // S(c0) before R(c0): S = oldest 8
    int4 acur[4];
    float4 scur[4];
#pragma unroll
    for (int ks = 0; ks < 2; ks++) {
        acur[2 * ks]     = *(const int4*)(adjrow + ks * 32 + quad * 8);
        acur[2 * ks + 1] = *(const int4*)(adjrow + ks * 32 + quad * 8 + 4);
        scur[2 * ks]     = *(const float4*)(s2b + ks * 32 + quad * 8);
        scur[2 * ks + 1] = *(const float4*)(s2b + ks * 32 + quad * 8 + 4);
    }
    // vmcnt(8): S(c0) complete (8 oldest of 16 outstanding); R(c0) in flight.
    asm volatile("s_waitcnt vmcnt(8)" ::: "memory");
    __builtin_amdgcn_s_barrier();
    asm volatile("" ::: "memory");

    f32x4 acc[8];
#pragma unroll
    for (int ot = 0; ot < 8; ot++) acc[ot] = (f32x4){0.f, 0.f, 0.f, 0.f};
    float rs_loc = 0.f;

    for (int k = 0; k < NCHL; k++) {
        const int buf = k & 1;
        const bool more = (k + 1 < NCHL);
        int4 anext[4];
        float4 snext[4];
        if (more) {
            // S(c_{k+1}): stays ahead of R in the queue (fence below)
#pragma unroll
            for (int q = 0; q < 4; q++)
                gl2lds16(&hTc[(size_t)(k + 1) * CHUNK_U4 + (rh * 4 + q) * 64 + lane],
                         &hbuf[jh][buf ^ 1][(rh * 4 + q) * 64]);
            asm volatile("" ::: "memory");
            const int j1 = (k + 1) * TJ;
#pragma unroll
            for (int ks = 0; ks < 2; ks++) {
                anext[2 * ks]     = *(const int4*)(adjrow + j1 + ks * 32 + quad * 8);
                anext[2 * ks + 1] = *(const int4*)(adjrow + j1 + ks * 32 + quad * 8 + 4);
                snext[2 * ks]     = *(const float4*)(s2b + j1 + ks * 32 + quad * 8);
                snext[2 * ks + 1] = *(const float4*)(s2b + j1 + ks * 32 + quad * 8 + 4);
            }
        }

        // ---- compute chunk k (registers + LDS only; no VMEM) ----
#pragma unroll
        for (int ks = 0; ks < 2; ks++) {
            float4 sa = scur[2 * ks], sb = scur[2 * ks + 1];
            float sarr[8] = {sa.x, sa.y, sa.z, sa.w, sb.x, sb.y, sb.z, sb.w};
            int4 A0 = acur[2 * ks], A1 = acur[2 * ks + 1];
            int aarr[8] = {A0.x, A0.y, A0.z, A0.w, A1.x, A1.y, A1.z, A1.w};
            union { unsigned short us[8]; short8 v; } af;
#pragma unroll
            for (int jj = 0; jj < 8; jj++) {
                float e = s1v + sarr[jj];
                e = (e > 0.f) ? e : (ALPHA_ * e);
                float p = (aarr[jj] > 0) ? __expf(e) : 0.f;
                rs_loc += p;
                af.us[jj] = f2bf(p);
            }
            const int jc = ks * 4 + quad;  // B-frag 16B-chunk index
#pragma unroll
            for (int ot = 0; ot < 8; ot++) {
                const int o = ot * 16 + m;  // B-frag n = lane&15
                union { uint4 u; short8 v; } bf;
                bf.u = *(const uint4*)&hbuf[jh][buf][HC64(o, jc)];
                acc[ot] = __builtin_amdgcn_mfma_f32_16x16x32_bf16(af.v, bf.v, acc[ot], 0, 0, 0);
            }
        }

        // Counted wait: S(c_{k+1}) = oldest 8 done; adj/s2 R(c_{k+1}) (8)
        // stay in flight across the barrier (compiler waits before their use).
        asm volatile("s_waitcnt vmcnt(8)" ::: "memory");
        __builtin_amdgcn_s_barrier();
        asm volatile("" ::: "memory");
        if (more) {
#pragma unroll
            for (int q = 0; q < 4; q++) { acur[q] = anext[q]; scur[q] = snext[q]; }
        }
    }

    // ---- rowsum: lanes m, m+16, m+32, m+48 hold partials of row m ----
    rs_loc += __shfl_xor(rs_loc, 16);
    rs_loc += __shfl_xor(rs_loc, 32);

    // ---- cross-j-half combine via LDS (reuse hbuf; last barrier above) ----
    float* xch = (float*)&hbuf[0][0][0];   // [64 rows][130] = 33.3 KB
    if (jh == 1) {
#pragma unroll
        for (int ot = 0; ot < 8; ot++)
#pragma unroll
            for (int r = 0; r < 4; r++)
                xch[(rh * 16 + quad * 4 + r) * 130 + ot * 16 + m] = acc[ot][r];
        if (quad == 0) rsx[rh][m] = rs_loc;
    }
    __syncthreads();
    if (jh == 0) {
        float rinv[4];
#pragma unroll
        for (int r = 0; r < 4; r++) {
            const int p = quad * 4 + r;
            rinv[r] = 1.0f / (__shfl(rs_loc, p) + rsx[rh][p]);
        }
        float* outp = out + (size_t)(b * N_ + i0 + rh * 16) * FD;
#pragma unroll
        for (int ot = 0; ot < 8; ot++) {
            const int col = ot * 16 + m;
#pragma unroll
            for (int r = 0; r < 4; r++) {
                float v = acc[ot][r] + xch[(rh * 16 + quad * 4 + r) * 130 + col];
                outp[(size_t)(quad * 4 + r) * FD + col] = v * rinv[r];
            }
        }
    }
}

// ---------------------------------------------------------------------------
extern "C" void kernel_launch(void* const* d_in, const int* in_sizes, int n_in,
                              void* d_out, int out_size, void* d_ws, size_t ws_size,
                              hipStream_t stream) {
    const void* xv = d_in[0];
    const void* adjv = d_in[1];
    const void* Wv = d_in[2];
    const void* av = d_in[3];
    for (int i = 0; i < n_in; i++) {
        switch (in_sizes[i]) {
            case 2097152:  xv = d_in[i]; break;
            case 33554432: adjv = d_in[i]; break;
            case 16384:    Wv = d_in[i]; break;
            case 256:      av = d_in[i]; break;
            default: break;
        }
    }
    const float* x = (const float*)xv;
    const int* adj = (const int*)adjv;
    const float* W = (const float*)Wv;
    const float* a = (const float*)av;
    float* out = (float*)d_out;

    // ws: hT 4MB | s1 64KB | s2 64KB
    char* p = (char*)d_ws;
    unsigned short* hT = (unsigned short*)p;  p += (size_t)B_ * FD * N_ * 2;
    float* s1 = (float*)p;                    p += (size_t)B_ * N_ * 4;
    float* s2 = (float*)p;

    gat_h<<<256, 256, 0, stream>>>(x, W, a, hT, s1, s2);
    gat_attn<<<256, 512, 0, stream>>>(adj, hT, s1, s2, out);
}

// Round 7
// 216.179 us; speedup vs baseline: 1.1758x; 1.0428x over previous
//
#include <hip/hip_runtime.h>
#include <stdint.h>

// GAT layer on MI355X: B=8, N=2048, F=128.
// h = x@W^T ; s1=h@a1 ; s2=h@a2 ; e=leaky(s1[i]+s2[j]); masked softmax; out=attn@h
//
// R7: occupancy round. Evidence: R0 (r32, 2 blk/CU, 402MB) = 63us attn beats
// r64 (1 blk/CU, 276MB) = 70-74us even with counted-vmcnt (R6 neutral) ->
// latency-bound at 8 waves/CU, not BW- or drain-bound. Fix: TJ=32 (8KB
// chunks) so an r32 block with 512 thr (8 waves = 2 rh x 4 j-quarters) fits
// ring-2 LDS in 64KB -> 2 blocks/CU x 8 waves = 16 waves/CU (2x R0), grid
// 512, traffic/barrier-cadence identical to R0. hT global layout = 8KB
// chunks, row-pair-interleaved XOR swizzle U32 (bijective; conflict-free
// for ds_read_b128 under 8-lane phasing, same property as proven HC64).
//
// K1 (gat_h): same MFMA pipeline; epilogue writes the U32-swizzled 8KB-chunk
//     layout (staging in K2 stays an identity gl2lds copy).

#define B_ 8
#define N_ 2048
#define FD 128
#define ALPHA_ 0.2f
#define TJ 32
#define NCH 16                    // chunks per j-quarter (512/32)
#define CHU4 512                  // u4 per chunk: 128 o x 4 u4 (8 KB)

typedef __attribute__((ext_vector_type(8))) short short8;
typedef __attribute__((ext_vector_type(4))) float f32x4;

// 4-bit XOR swizzle for the 128x128 W tile in gat_h (16B-chunk units)
#define HCHUNK(o, jc) ((((o) * 16) + ((jc) ^ ((o) & 15))) * 8)  // ushort offset
// row-pair interleaved swizzle for 128x32 hT chunks (uint4 units)
// o in [0,128), jc in [0,4): bijective onto [0,512)
#define U32(o, jc) (((o) >> 1) * 8 + ((((((o) & 1) << 2)) | (jc)) ^ (((o) >> 1) & 7)))

__device__ __forceinline__ float bf2f(unsigned short u) {
    union { uint32_t i; float f; } v; v.i = ((uint32_t)u) << 16; return v.f;
}
__device__ __forceinline__ unsigned short f2bf(float f) {
    union { float f; uint32_t i; } v; v.f = f;
    uint32_t x = v.i;
    uint32_t r = (x + 0x7fffu + ((x >> 16) & 1u)) >> 16;  // RNE
    return (unsigned short)r;
}

// async global->LDS, 16B per lane. lds dst must be wave-uniform base;
// HW writes base + lane*16 (m104/m108). Our staging is an identity copy.
__device__ __forceinline__ void gl2lds16(const uint4* g, uint4* l) {
    __builtin_amdgcn_global_load_lds(
        (const __attribute__((address_space(1))) uint32_t*)g,
        (__attribute__((address_space(3))) uint32_t*)l, 16, 0, 0);
}

// ---------------------------------------------------------------------------
// Kernel 1: h = x@W^T via split-bf16 MFMA; writes U32-chunked hT + s1/s2.
// 256 blocks x 256 threads; block = 64 rows x 128 outs; wave w: rows w*16..+16.
// C/D: col=lane&15, row=quad*4+reg  (m89/m91-verified layout).
// ---------------------------------------------------------------------------
__global__ __launch_bounds__(256) void gat_h(
    const float* __restrict__ x,
    const float* __restrict__ W,
    const float* __restrict__ a,
    unsigned short* __restrict__ hT,   // chunked: [b][kc32][U32(o,jc2)*8 + (j&7)]
    float* __restrict__ s1o, float* __restrict__ s2o)
{
    __shared__ __align__(16) unsigned short Wlds[FD * FD];  // 32KB, swizzled

    const int bid = blockIdx.x;
    const int tid = threadIdx.x;
    const int w = tid >> 6;
    const int lane = tid & 63;
    const int m = lane & 15;
    const int quad = lane >> 4;
    const int arow = bid * 64 + w * 16 + m;   // A-operand row for this lane

    // ---- stage W (fp32 -> bf16) into swizzled LDS, once per block ----
#pragma unroll
    for (int it = 0; it < 8; it++) {
        int cid = it * 256 + tid;          // 2048 16B-chunks
        int o = cid >> 4, kc = cid & 15;
        const float* wp = W + (size_t)o * FD + kc * 8;
        float4 w0 = *(const float4*)wp;
        float4 w1 = *(const float4*)(wp + 4);
        uint4 pk;
        pk.x = (uint32_t)f2bf(w0.x) | ((uint32_t)f2bf(w0.y) << 16);
        pk.y = (uint32_t)f2bf(w0.z) | ((uint32_t)f2bf(w0.w) << 16);
        pk.z = (uint32_t)f2bf(w1.x) | ((uint32_t)f2bf(w1.y) << 16);
        pk.w = (uint32_t)f2bf(w1.z) | ((uint32_t)f2bf(w1.w) << 16);
        *(uint4*)&Wlds[HCHUNK(o, kc)] = pk;
    }
    __syncthreads();

    f32x4 acc[8];
#pragma unroll
    for (int ot = 0; ot < 8; ot++) acc[ot] = (f32x4){0.f, 0.f, 0.f, 0.f};

#pragma unroll
    for (int ks = 0; ks < 4; ks++) {
        const float* xp = x + (size_t)arow * FD + ks * 32 + quad * 8;
        float4 x0 = *(const float4*)xp;
        float4 x1 = *(const float4*)(xp + 4);
        float xv[8] = {x0.x, x0.y, x0.z, x0.w, x1.x, x1.y, x1.z, x1.w};
        union { unsigned short us[8]; short8 v; } ahi, alo;
#pragma unroll
        for (int jj = 0; jj < 8; jj++) {
            unsigned short hi = f2bf(xv[jj]);
            ahi.us[jj] = hi;
            alo.us[jj] = f2bf(xv[jj] - bf2f(hi));
        }
#pragma unroll
        for (int ot = 0; ot < 8; ot++) {
            union { uint4 u; short8 v; } bw;
            bw.u = *(const uint4*)&Wlds[HCHUNK(ot * 16 + m, ks * 4 + quad)];
            acc[ot] = __builtin_amdgcn_mfma_f32_16x16x32_bf16(ahi.v, bw.v, acc[ot], 0, 0, 0);
            acc[ot] = __builtin_amdgcn_mfma_f32_16x16x32_bf16(alo.v, bw.v, acc[ot], 0, 0, 0);
        }
    }

    // Epilogue: store hT (U32-chunked, bf16) + s1/s2 partial reduce.
    const int rc0 = bid * 64 + w * 16 + quad * 4;  // C rows rc0..rc0+3 (= j)
    const int bb = rc0 >> 11;                      // batch
    const int jb = rc0 & (N_ - 1);
    const int kc = jb >> 5;                        // 32-j chunk
    const int jc2 = (jb & 31) >> 3;                // u4 j-slot in chunk
    const int off = jb & 7;                        // 0 or 4
    unsigned short* hTb = hT + (size_t)bb * FD * N_ + (size_t)kc * (CHU4 * 8);
    float s1p[4] = {0.f, 0.f, 0.f, 0.f};
    float s2p[4] = {0.f, 0.f, 0.f, 0.f};
#pragma unroll
    for (int ot = 0; ot < 8; ot++) {
        const int o = ot * 16 + m;
        uint2 pk;
        pk.x = (uint32_t)f2bf(acc[ot][0]) | ((uint32_t)f2bf(acc[ot][1]) << 16);
        pk.y = (uint32_t)f2bf(acc[ot][2]) | ((uint32_t)f2bf(acc[ot][3]) << 16);
        *(uint2*)(hTb + (size_t)U32(o, jc2) * 8 + off) = pk;
        float a1v = a[o], a2v = a[FD + o];
#pragma unroll
        for (int r = 0; r < 4; r++) {
            s1p[r] += acc[ot][r] * a1v;
            s2p[r] += acc[ot][r] * a2v;
        }
    }
#pragma unroll
    for (int offx = 8; offx >= 1; offx >>= 1) {
#pragma unroll
        for (int r = 0; r < 4; r++) {
            s1p[r] += __shfl_xor(s1p[r], offx);
            s2p[r] += __shfl_xor(s2p[r], offx);
        }
    }
    if (m == 0) {
#pragma unroll
        for (int r = 0; r < 4; r++) {
            s1o[rc0 + r] = s1p[r];
            s2o[rc0 + r] = s2p[r];
        }
    }
}

// ---------------------------------------------------------------------------
// Kernel 2: fused masked-softmax + PV (MFMA), 16 waves/CU.
// 512 blocks (b=bid&7 XCD-pin, i0=(bid>>3)*32) x 512 thr (8 waves).
// Wave w: rh=w&1 (rows [i0+rh*16,+16)), jq=w>>1 (j in [jq*512,+512)).
// Per jq: 16 chunks of 32 j, ring-2 LDS (8KB each), staged by the jq's two
// rh-waves via gl2lds identity copy. adj/s2 reg-prefetched one chunk ahead.
// LDS 64KB+rsq -> 2 blocks/CU = 16 waves/CU. Plain __syncthreads (R0-proven).
// Epilogue: jq>0 push acc/rowsum via LDS; jq=0 combines, divides, writes.
// ---------------------------------------------------------------------------
__global__ __launch_bounds__(512, 4) void gat_attn(
    const int* __restrict__ adj,
    const unsigned short* __restrict__ hT,
    const float* __restrict__ s1,
    const float* __restrict__ s2,
    float* __restrict__ out)
{
    __shared__ __align__(16) uint4 hbuf[4][2][CHU4];  // [jq][buf], 64 KB
    __shared__ float rsq[4][2][16];                   // per-(jq,rh) rowsums

    const int bid = blockIdx.x;
    const int b = bid & 7;              // batch -> XCD pin
    const int ib = bid >> 3;            // 0..63
    const int i0 = ib * 32;
    const int tid = threadIdx.x;
    const int lane = tid & 63;
    const int w = tid >> 6;             // 0..7
    const int rh = w & 1;               // row-group
    const int jq = w >> 1;              // j-quarter 0..3
    const int m = lane & 15;
    const int quad = lane >> 4;

    const int irow = i0 + rh * 16 + m;     // this lane's P row (A-frag m)
    const float s1v = s1[b * N_ + irow];
    const int* adjrow = adj + ((size_t)(b * N_ + irow)) * N_ + jq * 512;
    const float* s2q = s2 + b * N_ + jq * 512;
    const uint4* hTq = (const uint4*)hT + (size_t)b * (FD * N_ / 8)
                       + (size_t)jq * NCH * CHU4;

    // ---- prologue: stage chunk 0 (both rh-waves of the jq: 2x256 u4) ----
#pragma unroll
    for (int q = 0; q < 4; q++)
        gl2lds16(&hTq[rh * 256 + q * 64 + lane], &hbuf[jq][0][rh * 256 + q * 64]);
    int4 a0 = *(const int4*)(adjrow + quad * 8);
    int4 a1 = *(const int4*)(adjrow + quad * 8 + 4);
    float4 sc0 = *(const float4*)(s2q + quad * 8);
    float4 sc1 = *(const float4*)(s2q + quad * 8 + 4);
    __syncthreads();

    f32x4 acc[8];
#pragma unroll
    for (int ot = 0; ot < 8; ot++) acc[ot] = (f32x4){0.f, 0.f, 0.f, 0.f};
    float rs_loc = 0.f;

    for (int k = 0; k < NCH; k++) {
        const int buf = k & 1;
        const bool more = (k + 1 < NCH);
        int4 na0, na1;
        float4 ns0, ns1;
        if (more) {
            // stage chunk k+1 (in flight across compute; barrier drains)
#pragma unroll
            for (int q = 0; q < 4; q++)
                gl2lds16(&hTq[(size_t)(k + 1) * CHU4 + rh * 256 + q * 64 + lane],
                         &hbuf[jq][buf ^ 1][rh * 256 + q * 64]);
            const int j1 = (k + 1) * TJ;
            na0 = *(const int4*)(adjrow + j1 + quad * 8);
            na1 = *(const int4*)(adjrow + j1 + quad * 8 + 4);
            ns0 = *(const float4*)(s2q + j1 + quad * 8);
            ns1 = *(const float4*)(s2q + j1 + quad * 8 + 4);
        }

        // ---- compute chunk k: softmax on 8 j/lane + 8 MFMA (K=32) ----
        {
            float sarr[8] = {sc0.x, sc0.y, sc0.z, sc0.w, sc1.x, sc1.y, sc1.z, sc1.w};
            int aarr[8] = {a0.x, a0.y, a0.z, a0.w, a1.x, a1.y, a1.z, a1.w};
            union { unsigned short us[8]; short8 v; } af;
#pragma unroll
            for (int jj = 0; jj < 8; jj++) {
                float e = s1v + sarr[jj];
                e = (e > 0.f) ? e : (ALPHA_ * e);
                float p = (aarr[jj] > 0) ? __expf(e) : 0.f;
                rs_loc += p;
                af.us[jj] = f2bf(p);
            }
#pragma unroll
            for (int ot = 0; ot < 8; ot++) {
                const int o = ot * 16 + m;  // B-frag n = lane&15
                union { uint4 u; short8 v; } bf;
                bf.u = *(const uint4*)&hbuf[jq][buf][U32(o, quad)];
                acc[ot] = __builtin_amdgcn_mfma_f32_16x16x32_bf16(af.v, bf.v, acc[ot], 0, 0, 0);
            }
        }

        __syncthreads();  // drains vmcnt: chunk k+1 staged; safe to flip
        if (more) { a0 = na0; a1 = na1; sc0 = ns0; sc1 = ns1; }
    }

    // ---- rowsum: lanes m, m+16, m+32, m+48 hold partials of row m ----
    rs_loc += __shfl_xor(rs_loc, 16);
    rs_loc += __shfl_xor(rs_loc, 32);

    // ---- cross-jq combine via LDS (xch overlays hbuf; barrier above done) ----
    float* xch = (float*)&hbuf[0][0][0];   // [3][32][132] floats = 50.7 KB
    if (jq != 0) {
#pragma unroll
        for (int ot = 0; ot < 8; ot++)
#pragma unroll
            for (int r = 0; r < 4; r++)
                xch[((jq - 1) * 32 + rh * 16 + quad * 4 + r) * 132 + ot * 16 + m]
                    = acc[ot][r];
        if (quad == 0) rsq[jq][rh][m] = rs_loc;
    }
    __syncthreads();
    if (jq == 0) {
        float rinv[4];
#pragma unroll
        for (int r = 0; r < 4; r++) {
            const int p = quad * 4 + r;
            float rtot = __shfl(rs_loc, p)
                       + rsq[1][rh][p] + rsq[2][rh][p] + rsq[3][rh][p];
            rinv[r] = 1.0f / rtot;
        }
        float* outp = out + (size_t)(b * N_ + i0 + rh * 16) * FD;
#pragma unroll
        for (int ot = 0; ot < 8; ot++) {
            const int col = ot * 16 + m;
#pragma unroll
            for (int r = 0; r < 4; r++) {
                const int row = rh * 16 + quad * 4 + r;
                float v = acc[ot][r]
                        + xch[(row) * 132 + col]
                        + xch[(32 + row) * 132 + col]
                        + xch[(64 + row) * 132 + col];
                outp[(size_t)(quad * 4 + r) * FD + col] = v * rinv[r];
            }
        }
    }
}

// ---------------------------------------------------------------------------
extern "C" void kernel_launch(void* const* d_in, const int* in_sizes, int n_in,
                              void* d_out, int out_size, void* d_ws, size_t ws_size,
                              hipStream_t stream) {
    const void* xv = d_in[0];
    const void* adjv = d_in[1];
    const void* Wv = d_in[2];
    const void* av = d_in[3];
    for (int i = 0; i < n_in; i++) {
        switch (in_sizes[i]) {
            case 2097152:  xv = d_in[i]; break;
            case 33554432: adjv = d_in[i]; break;
            case 16384:    Wv = d_in[i]; break;
            case 256:      av = d_in[i]; break;
            default: break;
        }
    }
    const float* x = (const float*)xv;
    const int* adj = (const int*)adjv;
    const float* W = (const float*)Wv;
    const float* a = (const float*)av;
    float* out = (float*)d_out;

    // ws: hT 4MB | s1 64KB | s2 64KB
    char* p = (char*)d_ws;
    unsigned short* hT = (unsigned short*)p;  p += (size_t)B_ * FD * N_ * 2;
    float* s1 = (float*)p;                    p += (size_t)B_ * N_ * 4;
    float* s2 = (float*)p;

    gat_h<<<256, 256, 0, stream>>>(x, W, a, hT, s1, s2);
    gat_attn<<<512, 512, 0, stream>>>(adj, hT, s1, s2, out);
}